// Round 3
// baseline (940.003 us; speedup 1.0000x reference)
//
#include <hip/hip_runtime.h>

typedef unsigned short u16;
#define MB ((size_t)1 << 20)

typedef __attribute__((ext_vector_type(8))) short short8;   // 8 bf16 (4 VGPRs)
typedef __attribute__((ext_vector_type(4))) float float4v;  // 4 fp32 acc

__device__ __forceinline__ float bfu(u16 s) { return __uint_as_float(((unsigned)s) << 16); }
__device__ __forceinline__ u16 f2bf(float f) {
  unsigned u = __float_as_uint(f);
  return (u16)((u + 0x7fffu + ((u >> 16) & 1u)) >> 16);
}
__device__ __forceinline__ void async_ld16(const u16* g, u16* l) {
  __builtin_amdgcn_global_load_lds((const __attribute__((address_space(1))) unsigned*)g,
                                   (__attribute__((address_space(3))) unsigned*)l, 16, 0, 0);
}

// ---------------- f32 -> bf16 convert ----------------
__global__ __launch_bounds__(256)
void cvt_k(const float* __restrict__ in, u16* __restrict__ out, int n4) {
  int i = blockIdx.x * 256 + threadIdx.x;
  if (i >= n4) return;
  float4 v = ((const float4*)in)[i];
  ushort4 p;
  p.x = f2bf(v.x); p.y = f2bf(v.y); p.z = f2bf(v.z); p.w = f2bf(v.w);
  ((ushort4*)out)[i] = p;
}

// ---------------- RMSNorm (f32 in): one block per 1024-elem row ----------------
__global__ __launch_bounds__(256)
void rmsnorm_k(const float* __restrict__ x, const float* __restrict__ g,
               u16* __restrict__ o) {
  int row = blockIdx.x;
  int t = threadIdx.x;
  float4 v = ((const float4*)(x + (size_t)row * 1024))[t];
  float ss = v.x * v.x + v.y * v.y + v.z * v.z + v.w * v.w;
#pragma unroll
  for (int d = 32; d; d >>= 1) ss += __shfl_down(ss, d);
  __shared__ float r[4];
  if ((t & 63) == 0) r[t >> 6] = ss;
  __syncthreads();
  float rinv = rsqrtf((r[0] + r[1] + r[2] + r[3]) * (1.0f / 1024.0f) + 1e-6f);
  float4 gv = ((const float4*)g)[t];
  ushort4 p;
  p.x = f2bf(v.x * rinv * gv.x);
  p.y = f2bf(v.y * rinv * gv.y);
  p.z = f2bf(v.z * rinv * gv.z);
  p.w = f2bf(v.w * rinv * gv.w);
  ((ushort4*)(o + (size_t)row * 1024))[t] = p;
}

// ---------------- RMSNorm (bf16 in) ----------------
__global__ __launch_bounds__(256)
void rmsnorm_bf_k(const u16* __restrict__ x, const float* __restrict__ g,
                  u16* __restrict__ o) {
  int row = blockIdx.x;
  int t = threadIdx.x;
  ushort4 v = ((const ushort4*)(x + (size_t)row * 1024))[t];
  float f0 = bfu(v.x), f1 = bfu(v.y), f2 = bfu(v.z), f3 = bfu(v.w);
  float ss = f0 * f0 + f1 * f1 + f2 * f2 + f3 * f3;
#pragma unroll
  for (int d = 32; d; d >>= 1) ss += __shfl_down(ss, d);
  __shared__ float r[4];
  if ((t & 63) == 0) r[t >> 6] = ss;
  __syncthreads();
  float rinv = rsqrtf((r[0] + r[1] + r[2] + r[3]) * (1.0f / 1024.0f) + 1e-6f);
  float4 gv = ((const float4*)g)[t];
  ushort4 p;
  p.x = f2bf(f0 * rinv * gv.x);
  p.y = f2bf(f1 * rinv * gv.y);
  p.z = f2bf(f2 * rinv * gv.z);
  p.w = f2bf(f3 * rinv * gv.w);
  ((ushort4*)(o + (size_t)row * 1024))[t] = p;
}

// ---------------- MFMA GEMM (m97 structure): C[M,N] = A[M,K] @ B[N,K]^T ----------------
// XCD-aware block swizzle (bijective: all grids here have nwg % 8 == 0).
template <int EPI>
__global__ __launch_bounds__(256)
void gemm_mfma(const u16* __restrict__ A, const u16* __restrict__ B,
               const float* __restrict__ bias, const void* __restrict__ res,
               void* __restrict__ outp, int M, int N, int K) {
  __shared__ u16 As[128 * 32];
  __shared__ u16 Bs[128 * 32];
  int t = threadIdx.x;
  unsigned gx = gridDim.x;
  unsigned nwg = gx * gridDim.y;
  unsigned flat = blockIdx.y * gx + blockIdx.x;
  unsigned cpx = nwg >> 3;
  unsigned swz = (flat & 7) * cpx + (flat >> 3);
  int m0 = (int)(swz / gx) * 128, n0 = (int)(swz % gx) * 128;
  int w = t >> 6, lane = t & 63;
  int quad = lane >> 4, l16 = lane & 15;
  int wm = w >> 1, wn = w & 1;

  float4v acc[4][4];
#pragma unroll
  for (int mi = 0; mi < 4; mi++)
#pragma unroll
    for (int ni = 0; ni < 4; ni++) acc[mi][ni] = (float4v){0.f, 0.f, 0.f, 0.f};

  const u16* ga = A + (size_t)(m0 + (t >> 2)) * K + (t & 3) * 8;
  const u16* gb = B + (size_t)(n0 + (t >> 2)) * K + (t & 3) * 8;
  u16* la = As + w * 512;
  u16* lb = Bs + w * 512;
  const size_t rstep = (size_t)64 * K;

  for (int k0 = 0; k0 < K; k0 += 32) {
    async_ld16(ga + k0, la);
    async_ld16(ga + rstep + k0, la + 2048);
    async_ld16(gb + k0, lb);
    async_ld16(gb + rstep + k0, lb + 2048);
    __syncthreads();

    short8 af[4], bf[4];
#pragma unroll
    for (int i = 0; i < 4; i++)
      af[i] = *(const short8*)&As[(wm * 64 + i * 16 + l16) * 32 + quad * 8];
#pragma unroll
    for (int i = 0; i < 4; i++)
      bf[i] = *(const short8*)&Bs[(wn * 64 + i * 16 + l16) * 32 + quad * 8];
#pragma unroll
    for (int mi = 0; mi < 4; mi++)
#pragma unroll
      for (int ni = 0; ni < 4; ni++)
        acc[mi][ni] = __builtin_amdgcn_mfma_f32_16x16x32_bf16(af[mi], bf[ni],
                                                              acc[mi][ni], 0, 0, 0);
    __syncthreads();
  }

  int rbase = m0 + wm * 64;
  int cbase = n0 + wn * 64;
  float bv[4];
#pragma unroll
  for (int ni = 0; ni < 4; ni++) bv[ni] = bias[cbase + ni * 16 + l16];
#pragma unroll
  for (int mi = 0; mi < 4; mi++) {
#pragma unroll
    for (int r = 0; r < 4; r++) {
      int row = rbase + mi * 16 + quad * 4 + r;
#pragma unroll
      for (int ni = 0; ni < 4; ni++) {
        int col = cbase + ni * 16 + l16;
        float o = acc[mi][ni][r] + bv[ni];
        if (EPI == 1) o = o / (1.0f + __expf(-o));
        if (EPI == 3) o += ((const float*)res)[(size_t)row * N + col];
        if (EPI == 4) o += bfu(((const u16*)res)[(size_t)row * N + col]);
        if (EPI == 4)
          ((float*)outp)[(size_t)row * N + col] = o;
        else
          ((u16*)outp)[(size_t)row * N + col] = f2bf(o);
      }
    }
  }
}

// ---------------- Flash attention v4: paired q-tiles, late V-transpose, pinned regs ---
// Changes vs v3 (counter-driven):
//  * amdgpu_waves_per_eu(3,3): LDS caps residency at 3 blocks/CU anyway; pin the
//    register budget at 512/3=168 so the allocator stops squeezing to 84 + spilling
//    (v3: WRITE_SIZE 46 MB vs 16.8 ideal = scratch).
//  * V transpose moved to END of iteration: V-load latency covered by the whole
//    iteration's compute even in B-only iterations (v3 exposed full latency there).
//  * bias-B prefetched a FULL iteration ahead (bvBn at top, 16-mov rotate at end);
//    bias-A prefetched during phase B (unchanged).
//  * grid transposed to (bh, pair): consecutive flat ids share bh%8 -> all 16
//    pair-blocks of one (b,h) on one XCD -> K/V (512 KB) L2-resident.
#define QKVS 3072

__global__ __launch_bounds__(256)
__attribute__((amdgpu_waves_per_eu(3, 3)))
void attn_mfma_k(const u16* __restrict__ QKV, const float* __restrict__ bias,
                 u16* __restrict__ O) {
  const int L = 2048, Dm = 1024;
  __shared__ u16 Ks[2][64 * 64];   // K tiles, async-staged, chunk-swizzled
  __shared__ u16 Vts[2][64][72];   // V^T [d][key], swizzled transpose writes
  __shared__ u16 QP[64][72];       // Q-A staging (prologue) -> P tiles (loop)

  int t = threadIdx.x;
  int p = blockIdx.y;              // pair index 0..15
  int qtA = p, qtB = 31 - p;
  int nj = qtB + 1;                // j-tiles: 0..qtB
  int bh = blockIdx.x;             // bh fastest -> same (b,h) pairs share XCD
  int h = bh >> 2, b = bh & 3;
  size_t base = ((size_t)b * L) * QKVS + (size_t)h * 64;
  const u16* Qp = QKV + base;
  const u16* Kp = QKV + base + 1024;
  const u16* Vp = QKV + base + 2048;
  size_t obase = ((size_t)b * L) * Dm + (size_t)h * 64;
  const float* brow = bias + (size_t)h * L * L;

  int w = t >> 6, lane = t & 63, quad = lane >> 4, l16 = lane & 15;
  int rA = qtA * 64 + w * 16 + quad * 4;   // global q-row base, tile A
  int rB = qtB * 64 + w * 16 + quad * 4;   // tile B

  // -------- prologue: issue all tile-0 loads, stage Q tiles --------
  int qrow = t >> 2, qd0 = (t & 3) * 16;
  const u16* qsA = Qp + (size_t)(qtA * 64 + qrow) * QKVS + qd0;
  const u16* qsB = Qp + (size_t)(qtB * 64 + qrow) * QKVS + qd0;
  uint4 qa0 = *(const uint4*)qsA;
  uint4 qa1 = *(const uint4*)(qsA + 8);
  uint4 qb0 = *(const uint4*)qsB;
  uint4 qb1 = *(const uint4*)(qsB + 8);

  int vkp = t >> 3, vd0 = (t & 7) * 8;     // key-pair 0..31, d-base
  const u16* vsrc = Vp + (size_t)(2 * vkp) * QKVS + vd0;
  union U8 { uint4 v; u16 e[8]; };
  U8 va, vb;
  va.v = *(const uint4*)vsrc;
  vb.v = *(const uint4*)(vsrc + QKVS);

  int krow = t >> 3;
  int kcc = ((t & 7) ^ (krow & 7)) * 8;    // pre-swizzled global source for linear DMA
  const u16* gk = Kp + (size_t)krow * QKVS + kcc;
  async_ld16(gk, Ks[0] + w * 512);
  async_ld16(gk + (size_t)32 * QKVS, Ks[0] + w * 512 + 2048);

  float bvA[4][4], bvB[4][4];
#pragma unroll
  for (int t4 = 0; t4 < 4; t4++)
#pragma unroll
    for (int r = 0; r < 4; r++) {
      bvA[t4][r] = brow[(size_t)(rA + r) * L + t4 * 16 + l16];
      bvB[t4][r] = brow[(size_t)(rB + r) * L + t4 * 16 + l16];
    }

  *(uint4*)&QP[qrow][qd0] = qa0;           // Q-A -> QP
  *(uint4*)&QP[qrow][qd0 + 8] = qa1;
  *(uint4*)&Vts[1][qrow][qd0] = qb0;       // Q-B parked in Vts[1] (overwritten at j=0 staging)
  *(uint4*)&Vts[1][qrow][qd0 + 8] = qb1;
#pragma unroll
  for (int i = 0; i < 8; i++) {            // V(0) transpose -> Vts[0], swizzled
    int row = vd0 + i;
    int ch = ((vkp >> 2) ^ (t & 7)) * 16 + (vkp & 3) * 4;
    *(unsigned*)((char*)&Vts[0][row][0] + ch) =
        (unsigned)va.e[i] | ((unsigned)vb.e[i] << 16);
  }
  __syncthreads();   // Q tiles + V(0) visible; K(0) DMA drained by barrier vmcnt

  short8 qfA0 = *(const short8*)&QP[w * 16 + l16][quad * 8];
  short8 qfA1 = *(const short8*)&QP[w * 16 + l16][32 + quad * 8];
  short8 qfB0 = *(const short8*)&Vts[1][w * 16 + l16][quad * 8];
  short8 qfB1 = *(const short8*)&Vts[1][w * 16 + l16][32 + quad * 8];
  __syncthreads();   // all q-frag reads done before Vts[1]/QP are overwritten in loop

  float4v accA[4], accB[4];
  float slA[4] = {0.f, 0.f, 0.f, 0.f}, slB[4] = {0.f, 0.f, 0.f, 0.f};
#pragma unroll
  for (int d4 = 0; d4 < 4; d4++) {
    accA[d4] = (float4v){0.f, 0.f, 0.f, 0.f};
    accB[d4] = (float4v){0.f, 0.f, 0.f, 0.f};
  }

  for (int j = 0; j < nj; j++) {
    int buf = j & 1, nb = buf ^ 1;
    int j0 = j * 64;
    int stage = (j + 1 < nj);
    int phA = (j <= qtA);
    int phAn = (j + 1 <= qtA);
    float bvBn[4][4];

    // ---- issue next-tile loads: V, K-DMA, then bias-B(j+1) (full-iter cover) ----
    if (stage) {
      va.v = *(const uint4*)(vsrc + (size_t)(j0 + 64) * QKVS);
      vb.v = *(const uint4*)(vsrc + (size_t)(j0 + 64) * QKVS + QKVS);
      async_ld16(gk + (size_t)(j0 + 64) * QKVS, Ks[nb] + w * 512);
      async_ld16(gk + (size_t)(j0 + 96) * QKVS, Ks[nb] + w * 512 + 2048);
#pragma unroll
      for (int t4 = 0; t4 < 4; t4++)
#pragma unroll
        for (int r = 0; r < 4; r++)
          bvBn[t4][r] = brow[(size_t)(rB + r) * L + (j0 + 64) + t4 * 16 + l16];
    }

    // ================= phase A (active while j <= qtA) =================
    if (phA) {
      __builtin_amdgcn_s_setprio(1);
      float4v s[4];
#pragma unroll
      for (int t4 = 0; t4 < 4; t4++) {
        int key = t4 * 16 + l16;
        const u16* kr = Ks[buf] + key * 64;
        int p0 = (quad ^ (key & 7)) * 8;
        short8 kf0 = *(const short8*)(kr + p0);
        short8 kf1 = *(const short8*)(kr + (p0 ^ 32));
        float4v z = (float4v){0.f, 0.f, 0.f, 0.f};
        z = __builtin_amdgcn_mfma_f32_16x16x32_bf16(qfA0, kf0, z, 0, 0, 0);
        z = __builtin_amdgcn_mfma_f32_16x16x32_bf16(qfA1, kf1, z, 0, 0, 0);
        s[t4] = z;
      }
      __builtin_amdgcn_s_setprio(0);
#pragma unroll
      for (int t4 = 0; t4 < 4; t4++) {
        int kidx = j0 + t4 * 16 + l16;
#pragma unroll
        for (int r = 0; r < 4; r++) {
          float pv = (kidx > rA + r) ? 0.f
                                     : __expf(fmaf(s[t4][r], 0.125f, bvA[t4][r]));
          slA[r] += pv;
          QP[w * 16 + quad * 4 + r][t4 * 16 + l16] = f2bf(pv);
        }
      }
      __builtin_amdgcn_s_setprio(1);
#pragma unroll
      for (int c = 0; c < 2; c++) {
        short8 pf = *(const short8*)&QP[w * 16 + l16][c * 32 + quad * 8];
#pragma unroll
        for (int d4 = 0; d4 < 4; d4++) {
          int row = d4 * 16 + l16;
          int ch = ((c * 4 + quad) ^ (2 * d4 + (l16 >> 3))) * 16;
          short8 vf = *(const short8*)((const char*)&Vts[buf][row][0] + ch);
          accA[d4] = __builtin_amdgcn_mfma_f32_16x16x32_bf16(pf, vf, accA[d4], 0, 0, 0);
        }
      }
      __builtin_amdgcn_s_setprio(0);
    }

    // ================= phase B (active every iteration) =================
    {
      __builtin_amdgcn_s_setprio(1);
      float4v s[4];
#pragma unroll
      for (int t4 = 0; t4 < 4; t4++) {
        int key = t4 * 16 + l16;
        const u16* kr = Ks[buf] + key * 64;
        int p0 = (quad ^ (key & 7)) * 8;
        short8 kf0 = *(const short8*)(kr + p0);
        short8 kf1 = *(const short8*)(kr + (p0 ^ 32));
        float4v z = (float4v){0.f, 0.f, 0.f, 0.f};
        z = __builtin_amdgcn_mfma_f32_16x16x32_bf16(qfB0, kf0, z, 0, 0, 0);
        z = __builtin_amdgcn_mfma_f32_16x16x32_bf16(qfB1, kf1, z, 0, 0, 0);
        s[t4] = z;
      }
      __builtin_amdgcn_s_setprio(0);
      // bias-A for NEXT iter (cover: softmax B + PV B + barrier + QK_A)
      if (phAn) {
#pragma unroll
        for (int t4 = 0; t4 < 4; t4++)
#pragma unroll
          for (int r = 0; r < 4; r++)
            bvA[t4][r] = brow[(size_t)(rA + r) * L + (j0 + 64) + t4 * 16 + l16];
      }
#pragma unroll
      for (int t4 = 0; t4 < 4; t4++) {
        int kidx = j0 + t4 * 16 + l16;
#pragma unroll
        for (int r = 0; r < 4; r++) {
          float pv = (kidx > rB + r) ? 0.f
                                     : __expf(fmaf(s[t4][r], 0.125f, bvB[t4][r]));
          slB[r] += pv;
          QP[w * 16 + quad * 4 + r][t4 * 16 + l16] = f2bf(pv);
        }
      }
      __builtin_amdgcn_s_setprio(1);
#pragma unroll
      for (int c = 0; c < 2; c++) {
        short8 pf = *(const short8*)&QP[w * 16 + l16][c * 32 + quad * 8];
#pragma unroll
        for (int d4 = 0; d4 < 4; d4++) {
          int row = d4 * 16 + l16;
          int ch = ((c * 4 + quad) ^ (2 * d4 + (l16 >> 3))) * 16;
          short8 vf = *(const short8*)((const char*)&Vts[buf][row][0] + ch);
          accB[d4] = __builtin_amdgcn_mfma_f32_16x16x32_bf16(pf, vf, accB[d4], 0, 0, 0);
        }
      }
      __builtin_amdgcn_s_setprio(0);
    }

    // ---- late V transpose into other buffer (V loads covered by whole iter) ----
    if (stage) {
#pragma unroll
      for (int i = 0; i < 8; i++) {
        int row = vd0 + i;
        int ch = ((vkp >> 2) ^ (t & 7)) * 16 + (vkp & 3) * 4;
        *(unsigned*)((char*)&Vts[nb][row][0] + ch) =
            (unsigned)va.e[i] | ((unsigned)vb.e[i] << 16);
      }
      // rotate bias-B double buffer (static indices -> pure v_movs)
#pragma unroll
      for (int t4 = 0; t4 < 4; t4++)
#pragma unroll
        for (int r = 0; r < 4; r++) bvB[t4][r] = bvBn[t4][r];
    }

    __syncthreads();  // next tile ready (DMA drained); buf reads done before reuse
  }

  // -------- epilogue: row-sum reduce, O = acc / l for both tiles --------
#pragma unroll
  for (int r = 0; r < 4; r++) {
    float sa = slA[r];
    sa += __shfl_xor(sa, 1); sa += __shfl_xor(sa, 2);
    sa += __shfl_xor(sa, 4); sa += __shfl_xor(sa, 8);
    float ia = 1.0f / sa;
    u16* oa = O + obase + (size_t)(rA + r) * Dm;
#pragma unroll
    for (int d4 = 0; d4 < 4; d4++) oa[d4 * 16 + l16] = f2bf(accA[d4][r] * ia);

    float sb = slB[r];
    sb += __shfl_xor(sb, 1); sb += __shfl_xor(sb, 2);
    sb += __shfl_xor(sb, 4); sb += __shfl_xor(sb, 8);
    float ib = 1.0f / sb;
    u16* ob = O + obase + (size_t)(rB + r) * Dm;
#pragma unroll
    for (int d4 = 0; d4 < 4; d4++) ob[d4 * 16 + l16] = f2bf(accB[d4][r] * ib);
  }
}

extern "C" void kernel_launch(void* const* d_in, const int* in_sizes, int n_in,
                              void* d_out, int out_size, void* d_ws, size_t ws_size,
                              hipStream_t stream) {
  const float* x = (const float*)d_in[0];
  const float* rb = (const float*)d_in[1];
  const float* wq = (const float*)d_in[2];
  const float* bq = (const float*)d_in[3];
  const float* wk = (const float*)d_in[4];
  const float* bk = (const float*)d_in[5];
  const float* wv = (const float*)d_in[6];
  const float* bv = (const float*)d_in[7];
  const float* wo = (const float*)d_in[8];
  const float* bo = (const float*)d_in[9];
  const float* n1w = (const float*)d_in[10];
  const float* n2w = (const float*)d_in[11];
  const float* w1 = (const float*)d_in[12];
  const float* b1 = (const float*)d_in[13];
  const float* w2 = (const float*)d_in[14];
  const float* b2 = (const float*)d_in[15];

  const int M = 8192, D = 1024, F = 4096;

  char* wsp = (char*)d_ws;
  u16* h = (u16*)(wsp);
  u16* ao = (u16*)(wsp);
  u16* f1 = (u16*)(wsp);
  u16* qkv = (u16*)(wsp + 16 * MB);
  u16* x1b = (u16*)(wsp + 64 * MB);
  u16* h2 = (u16*)(wsp + 80 * MB);
  float* bqkv = (float*)(wsp + 80 * MB);
  u16* wqkvb = (u16*)(wsp + 96 * MB);
  u16* wob = (u16*)(wsp + 102 * MB);
  u16* w1b = (u16*)(wsp + 104 * MB);
  u16* w2b = (u16*)(wsp + 96 * MB);

  dim3 blk(256);

  cvt_k<<<1024, blk, 0, stream>>>(wq, wqkvb, (D * D) / 4);
  cvt_k<<<1024, blk, 0, stream>>>(wk, wqkvb + D * D, (D * D) / 4);
  cvt_k<<<1024, blk, 0, stream>>>(wv, wqkvb + 2 * D * D, (D * D) / 4);
  cvt_k<<<1024, blk, 0, stream>>>(wo, wob, (D * D) / 4);
  cvt_k<<<4096, blk, 0, stream>>>(w1, w1b, (F * D) / 4);
  hipMemcpyAsync(bqkv, bq, D * 4, hipMemcpyDeviceToDevice, stream);
  hipMemcpyAsync(bqkv + D, bk, D * 4, hipMemcpyDeviceToDevice, stream);
  hipMemcpyAsync(bqkv + 2 * D, bv, D * 4, hipMemcpyDeviceToDevice, stream);

  rmsnorm_k<<<M, blk, 0, stream>>>(x, n1w, h);
  gemm_mfma<0><<<dim3(3 * D / 128, M / 128), blk, 0, stream>>>(
      h, wqkvb, bqkv, nullptr, qkv, M, 3 * D, D);
  attn_mfma_k<<<dim3(64, 16), blk, 0, stream>>>(qkv, rb, ao);
  gemm_mfma<3><<<dim3(D / 128, M / 128), blk, 0, stream>>>(
      ao, wob, bo, x, x1b, M, D, D);
  cvt_k<<<4096, blk, 0, stream>>>(w2, w2b, (D * F) / 4);
  rmsnorm_bf_k<<<M, blk, 0, stream>>>(x1b, n2w, h2);
  gemm_mfma<1><<<dim3(F / 128, M / 128), blk, 0, stream>>>(
      h2, w1b, b1, nullptr, f1, M, F, D);
  gemm_mfma<4><<<dim3(D / 128, M / 128), blk, 0, stream>>>(
      f1, w2b, b2, x1b, d_out, M, D, F);
}

// Round 4
// 878.640 us; speedup vs baseline: 1.0698x; 1.0698x over previous
//
#include <hip/hip_runtime.h>

typedef unsigned short u16;
#define MB ((size_t)1 << 20)

typedef __attribute__((ext_vector_type(8))) short short8;   // 8 bf16 (4 VGPRs)
typedef __attribute__((ext_vector_type(4))) float float4v;  // 4 fp32 acc

__device__ __forceinline__ float bfu(u16 s) { return __uint_as_float(((unsigned)s) << 16); }
__device__ __forceinline__ u16 f2bf(float f) {
  unsigned u = __float_as_uint(f);
  return (u16)((u + 0x7fffu + ((u >> 16) & 1u)) >> 16);
}
__device__ __forceinline__ void async_ld16(const u16* g, u16* l) {
  __builtin_amdgcn_global_load_lds((const __attribute__((address_space(1))) unsigned*)g,
                                   (__attribute__((address_space(3))) unsigned*)l, 16, 0, 0);
}

// ---------------- f32 -> bf16 convert ----------------
__global__ __launch_bounds__(256)
void cvt_k(const float* __restrict__ in, u16* __restrict__ out, int n4) {
  int i = blockIdx.x * 256 + threadIdx.x;
  if (i >= n4) return;
  float4 v = ((const float4*)in)[i];
  ushort4 p;
  p.x = f2bf(v.x); p.y = f2bf(v.y); p.z = f2bf(v.z); p.w = f2bf(v.w);
  ((ushort4*)out)[i] = p;
}

// ---------------- RMSNorm (f32 in): one block per 1024-elem row ----------------
__global__ __launch_bounds__(256)
void rmsnorm_k(const float* __restrict__ x, const float* __restrict__ g,
               u16* __restrict__ o) {
  int row = blockIdx.x;
  int t = threadIdx.x;
  float4 v = ((const float4*)(x + (size_t)row * 1024))[t];
  float ss = v.x * v.x + v.y * v.y + v.z * v.z + v.w * v.w;
#pragma unroll
  for (int d = 32; d; d >>= 1) ss += __shfl_down(ss, d);
  __shared__ float r[4];
  if ((t & 63) == 0) r[t >> 6] = ss;
  __syncthreads();
  float rinv = rsqrtf((r[0] + r[1] + r[2] + r[3]) * (1.0f / 1024.0f) + 1e-6f);
  float4 gv = ((const float4*)g)[t];
  ushort4 p;
  p.x = f2bf(v.x * rinv * gv.x);
  p.y = f2bf(v.y * rinv * gv.y);
  p.z = f2bf(v.z * rinv * gv.z);
  p.w = f2bf(v.w * rinv * gv.w);
  ((ushort4*)(o + (size_t)row * 1024))[t] = p;
}

// ---------------- RMSNorm (bf16 in) ----------------
__global__ __launch_bounds__(256)
void rmsnorm_bf_k(const u16* __restrict__ x, const float* __restrict__ g,
                  u16* __restrict__ o) {
  int row = blockIdx.x;
  int t = threadIdx.x;
  ushort4 v = ((const ushort4*)(x + (size_t)row * 1024))[t];
  float f0 = bfu(v.x), f1 = bfu(v.y), f2 = bfu(v.z), f3 = bfu(v.w);
  float ss = f0 * f0 + f1 * f1 + f2 * f2 + f3 * f3;
#pragma unroll
  for (int d = 32; d; d >>= 1) ss += __shfl_down(ss, d);
  __shared__ float r[4];
  if ((t & 63) == 0) r[t >> 6] = ss;
  __syncthreads();
  float rinv = rsqrtf((r[0] + r[1] + r[2] + r[3]) * (1.0f / 1024.0f) + 1e-6f);
  float4 gv = ((const float4*)g)[t];
  ushort4 p;
  p.x = f2bf(f0 * rinv * gv.x);
  p.y = f2bf(f1 * rinv * gv.y);
  p.z = f2bf(f2 * rinv * gv.z);
  p.w = f2bf(f3 * rinv * gv.w);
  ((ushort4*)(o + (size_t)row * 1024))[t] = p;
}

// ---------------- MFMA GEMM (m97 structure): C[M,N] = A[M,K] @ B[N,K]^T ----------------
// XCD-aware block swizzle (bijective: all grids here have nwg % 8 == 0).
template <int EPI>
__global__ __launch_bounds__(256)
void gemm_mfma(const u16* __restrict__ A, const u16* __restrict__ B,
               const float* __restrict__ bias, const void* __restrict__ res,
               void* __restrict__ outp, int M, int N, int K) {
  __shared__ u16 As[128 * 32];
  __shared__ u16 Bs[128 * 32];
  int t = threadIdx.x;
  unsigned gx = gridDim.x;
  unsigned nwg = gx * gridDim.y;
  unsigned flat = blockIdx.y * gx + blockIdx.x;
  unsigned cpx = nwg >> 3;
  unsigned swz = (flat & 7) * cpx + (flat >> 3);
  int m0 = (int)(swz / gx) * 128, n0 = (int)(swz % gx) * 128;
  int w = t >> 6, lane = t & 63;
  int quad = lane >> 4, l16 = lane & 15;
  int wm = w >> 1, wn = w & 1;

  float4v acc[4][4];
#pragma unroll
  for (int mi = 0; mi < 4; mi++)
#pragma unroll
    for (int ni = 0; ni < 4; ni++) acc[mi][ni] = (float4v){0.f, 0.f, 0.f, 0.f};

  const u16* ga = A + (size_t)(m0 + (t >> 2)) * K + (t & 3) * 8;
  const u16* gb = B + (size_t)(n0 + (t >> 2)) * K + (t & 3) * 8;
  u16* la = As + w * 512;
  u16* lb = Bs + w * 512;
  const size_t rstep = (size_t)64 * K;

  for (int k0 = 0; k0 < K; k0 += 32) {
    async_ld16(ga + k0, la);
    async_ld16(ga + rstep + k0, la + 2048);
    async_ld16(gb + k0, lb);
    async_ld16(gb + rstep + k0, lb + 2048);
    __syncthreads();

    short8 af[4], bf[4];
#pragma unroll
    for (int i = 0; i < 4; i++)
      af[i] = *(const short8*)&As[(wm * 64 + i * 16 + l16) * 32 + quad * 8];
#pragma unroll
    for (int i = 0; i < 4; i++)
      bf[i] = *(const short8*)&Bs[(wn * 64 + i * 16 + l16) * 32 + quad * 8];
#pragma unroll
    for (int mi = 0; mi < 4; mi++)
#pragma unroll
      for (int ni = 0; ni < 4; ni++)
        acc[mi][ni] = __builtin_amdgcn_mfma_f32_16x16x32_bf16(af[mi], bf[ni],
                                                              acc[mi][ni], 0, 0, 0);
    __syncthreads();
  }

  int rbase = m0 + wm * 64;
  int cbase = n0 + wn * 64;
  float bv[4];
#pragma unroll
  for (int ni = 0; ni < 4; ni++) bv[ni] = bias[cbase + ni * 16 + l16];
#pragma unroll
  for (int mi = 0; mi < 4; mi++) {
#pragma unroll
    for (int r = 0; r < 4; r++) {
      int row = rbase + mi * 16 + quad * 4 + r;
#pragma unroll
      for (int ni = 0; ni < 4; ni++) {
        int col = cbase + ni * 16 + l16;
        float o = acc[mi][ni][r] + bv[ni];
        if (EPI == 1) o = o / (1.0f + __expf(-o));
        if (EPI == 3) o += ((const float*)res)[(size_t)row * N + col];
        if (EPI == 4) o += bfu(((const u16*)res)[(size_t)row * N + col]);
        if (EPI == 4)
          ((float*)outp)[(size_t)row * N + col] = o;
        else
          ((u16*)outp)[(size_t)row * N + col] = f2bf(o);
      }
    }
  }
}

// ---------------- Flash attention v5: unconditional register-array defs ----------------
// Counter evidence r1-r3: VGPR_Count pinned at 84 under three occupancy directives while
// WRITE_SIZE tracked the number of CONDITIONALLY-defined register arrays -> the compiler
// demotes aggregates whose defs are control-dependent to scratch (rule-#20 sibling).
// Fix: every register-array def is unconditional; inactive iterations load from clamped
// dummy addresses (tile 0) and the values are never consumed.
//  * va/vb next-V loads: unconditional, base jn = stage ? j0+64 : 0.
//  * bvA reloaded in-place during phase B (jA clamped); bvB reloaded in-place after
//    softmax-B (cover = PV-B + V-transpose + barrier). No bvBn, no rotation movs.
//  * V-transpose unconditional (last iter writes the unread buffer).
//  * K-DMA conditional (uniform branch, no aggregates; must not be in flight at endpgm).
// Grid back to (pair, bh): blockIdx.x fastest -> 16 pair-blocks of one (b,h) adjacent,
// and the 4 batches of one h land on the same XCD residue (flat differs by 16 = 0 mod 8).
#define QKVS 3072

__global__ __launch_bounds__(256)
__attribute__((amdgpu_waves_per_eu(3, 3)))
void attn_mfma_k(const u16* __restrict__ QKV, const float* __restrict__ bias,
                 u16* __restrict__ O) {
  const int L = 2048, Dm = 1024;
  __shared__ u16 Ks[2][64 * 64];   // K tiles, async-staged, chunk-swizzled
  __shared__ u16 Vts[2][64][72];   // V^T [d][key], swizzled transpose writes
  __shared__ u16 QP[64][72];       // Q-A staging (prologue) -> P tiles (loop)

  int t = threadIdx.x;
  int p = blockIdx.x;              // pair index 0..15 (fastest -> same-bh adjacency)
  int qtA = p, qtB = 31 - p;
  int nj = qtB + 1;                // j-tiles: 0..qtB
  int bh = blockIdx.y;
  int h = bh >> 2, b = bh & 3;
  size_t base = ((size_t)b * L) * QKVS + (size_t)h * 64;
  const u16* Qp = QKV + base;
  const u16* Kp = QKV + base + 1024;
  const u16* Vp = QKV + base + 2048;
  size_t obase = ((size_t)b * L) * Dm + (size_t)h * 64;
  const float* brow = bias + (size_t)h * L * L;

  int w = t >> 6, lane = t & 63, quad = lane >> 4, l16 = lane & 15;
  int rA = qtA * 64 + w * 16 + quad * 4;   // global q-row base, tile A
  int rB = qtB * 64 + w * 16 + quad * 4;   // tile B

  // -------- prologue: issue all tile-0 loads, stage Q tiles --------
  int qrow = t >> 2, qd0 = (t & 3) * 16;
  const u16* qsA = Qp + (size_t)(qtA * 64 + qrow) * QKVS + qd0;
  const u16* qsB = Qp + (size_t)(qtB * 64 + qrow) * QKVS + qd0;
  uint4 qa0 = *(const uint4*)qsA;
  uint4 qa1 = *(const uint4*)(qsA + 8);
  uint4 qb0 = *(const uint4*)qsB;
  uint4 qb1 = *(const uint4*)(qsB + 8);

  int vkp = t >> 3, vd0 = (t & 7) * 8;     // key-pair 0..31, d-base
  const u16* vsrc = Vp + (size_t)(2 * vkp) * QKVS + vd0;
  union U8 { uint4 v; u16 e[8]; };
  U8 va, vb;
  va.v = *(const uint4*)vsrc;
  vb.v = *(const uint4*)(vsrc + QKVS);

  int krow = t >> 3;
  int kcc = ((t & 7) ^ (krow & 7)) * 8;    // pre-swizzled global source for linear DMA
  const u16* gk = Kp + (size_t)krow * QKVS + kcc;
  async_ld16(gk, Ks[0] + w * 512);
  async_ld16(gk + (size_t)32 * QKVS, Ks[0] + w * 512 + 2048);

  float bvA[4][4], bvB[4][4];
#pragma unroll
  for (int t4 = 0; t4 < 4; t4++)
#pragma unroll
    for (int r = 0; r < 4; r++) {
      bvA[t4][r] = brow[(size_t)(rA + r) * L + t4 * 16 + l16];
      bvB[t4][r] = brow[(size_t)(rB + r) * L + t4 * 16 + l16];
    }

  *(uint4*)&QP[qrow][qd0] = qa0;           // Q-A -> QP
  *(uint4*)&QP[qrow][qd0 + 8] = qa1;
  *(uint4*)&Vts[1][qrow][qd0] = qb0;       // Q-B parked in Vts[1] (overwritten at j=0 staging)
  *(uint4*)&Vts[1][qrow][qd0 + 8] = qb1;
#pragma unroll
  for (int i = 0; i < 8; i++) {            // V(0) transpose -> Vts[0], swizzled
    int row = vd0 + i;
    int ch = ((vkp >> 2) ^ (t & 7)) * 16 + (vkp & 3) * 4;
    *(unsigned*)((char*)&Vts[0][row][0] + ch) =
        (unsigned)va.e[i] | ((unsigned)vb.e[i] << 16);
  }
  __syncthreads();   // Q tiles + V(0) visible; K(0) DMA drained by barrier vmcnt

  short8 qfA0 = *(const short8*)&QP[w * 16 + l16][quad * 8];
  short8 qfA1 = *(const short8*)&QP[w * 16 + l16][32 + quad * 8];
  short8 qfB0 = *(const short8*)&Vts[1][w * 16 + l16][quad * 8];
  short8 qfB1 = *(const short8*)&Vts[1][w * 16 + l16][32 + quad * 8];
  __syncthreads();   // all q-frag reads done before Vts[1]/QP are overwritten in loop

  float4v accA[4], accB[4];
  float slA[4] = {0.f, 0.f, 0.f, 0.f}, slB[4] = {0.f, 0.f, 0.f, 0.f};
#pragma unroll
  for (int d4 = 0; d4 < 4; d4++) {
    accA[d4] = (float4v){0.f, 0.f, 0.f, 0.f};
    accB[d4] = (float4v){0.f, 0.f, 0.f, 0.f};
  }

  for (int j = 0; j < nj; j++) {
    int buf = j & 1, nb = buf ^ 1;
    int j0 = j * 64;
    int stage = (j + 1 < nj);
    int phA = (j <= qtA);
    int jn = stage ? j0 + 64 : 0;            // clamped next-tile base (dummy on last iter)
    int jA = (j + 1 <= qtA) ? j0 + 64 : 0;   // clamped next bias-A base

    // ---- next V loads (UNCONDITIONAL, clamped) + K-DMA (uniform conditional) ----
    va.v = *(const uint4*)(vsrc + (size_t)jn * QKVS);
    vb.v = *(const uint4*)(vsrc + (size_t)jn * QKVS + QKVS);
    if (stage) {
      async_ld16(gk + (size_t)jn * QKVS, Ks[nb] + w * 512);
      async_ld16(gk + (size_t)(jn + 32) * QKVS, Ks[nb] + w * 512 + 2048);
    }

    // ================= phase A (active while j <= qtA) =================
    if (phA) {
      __builtin_amdgcn_s_setprio(1);
      float4v s[4];
#pragma unroll
      for (int t4 = 0; t4 < 4; t4++) {
        int key = t4 * 16 + l16;
        const u16* kr = Ks[buf] + key * 64;
        int p0 = (quad ^ (key & 7)) * 8;
        short8 kf0 = *(const short8*)(kr + p0);
        short8 kf1 = *(const short8*)(kr + (p0 ^ 32));
        float4v z = (float4v){0.f, 0.f, 0.f, 0.f};
        z = __builtin_amdgcn_mfma_f32_16x16x32_bf16(qfA0, kf0, z, 0, 0, 0);
        z = __builtin_amdgcn_mfma_f32_16x16x32_bf16(qfA1, kf1, z, 0, 0, 0);
        s[t4] = z;
      }
      __builtin_amdgcn_s_setprio(0);
#pragma unroll
      for (int t4 = 0; t4 < 4; t4++) {
        int kidx = j0 + t4 * 16 + l16;
#pragma unroll
        for (int r = 0; r < 4; r++) {
          float pv = (kidx > rA + r) ? 0.f
                                     : __expf(fmaf(s[t4][r], 0.125f, bvA[t4][r]));
          slA[r] += pv;
          QP[w * 16 + quad * 4 + r][t4 * 16 + l16] = f2bf(pv);
        }
      }
      __builtin_amdgcn_s_setprio(1);
#pragma unroll
      for (int c = 0; c < 2; c++) {
        short8 pf = *(const short8*)&QP[w * 16 + l16][c * 32 + quad * 8];
#pragma unroll
        for (int d4 = 0; d4 < 4; d4++) {
          int row = d4 * 16 + l16;
          int ch = ((c * 4 + quad) ^ (2 * d4 + (l16 >> 3))) * 16;
          short8 vf = *(const short8*)((const char*)&Vts[buf][row][0] + ch);
          accA[d4] = __builtin_amdgcn_mfma_f32_16x16x32_bf16(pf, vf, accA[d4], 0, 0, 0);
        }
      }
      __builtin_amdgcn_s_setprio(0);
    }

    // ================= phase B (active every iteration) =================
    {
      __builtin_amdgcn_s_setprio(1);
      float4v s[4];
#pragma unroll
      for (int t4 = 0; t4 < 4; t4++) {
        int key = t4 * 16 + l16;
        const u16* kr = Ks[buf] + key * 64;
        int p0 = (quad ^ (key & 7)) * 8;
        short8 kf0 = *(const short8*)(kr + p0);
        short8 kf1 = *(const short8*)(kr + (p0 ^ 32));
        float4v z = (float4v){0.f, 0.f, 0.f, 0.f};
        z = __builtin_amdgcn_mfma_f32_16x16x32_bf16(qfB0, kf0, z, 0, 0, 0);
        z = __builtin_amdgcn_mfma_f32_16x16x32_bf16(qfB1, kf1, z, 0, 0, 0);
        s[t4] = z;
      }
      __builtin_amdgcn_s_setprio(0);
      // bvA reload for NEXT iter (UNCONDITIONAL, clamped; bvA dead after phase A above)
#pragma unroll
      for (int t4 = 0; t4 < 4; t4++)
#pragma unroll
        for (int r = 0; r < 4; r++)
          bvA[t4][r] = brow[(size_t)(rA + r) * L + jA + t4 * 16 + l16];
#pragma unroll
      for (int t4 = 0; t4 < 4; t4++) {
        int kidx = j0 + t4 * 16 + l16;
#pragma unroll
        for (int r = 0; r < 4; r++) {
          float pv = (kidx > rB + r) ? 0.f
                                     : __expf(fmaf(s[t4][r], 0.125f, bvB[t4][r]));
          slB[r] += pv;
          QP[w * 16 + quad * 4 + r][t4 * 16 + l16] = f2bf(pv);
        }
      }
      // bvB reload for NEXT iter (UNCONDITIONAL, clamped; bvB dead after softmax above;
      // cover = PV-B + V-transpose + barrier)
#pragma unroll
      for (int t4 = 0; t4 < 4; t4++)
#pragma unroll
        for (int r = 0; r < 4; r++)
          bvB[t4][r] = brow[(size_t)(rB + r) * L + jn + t4 * 16 + l16];
      __builtin_amdgcn_s_setprio(1);
#pragma unroll
      for (int c = 0; c < 2; c++) {
        short8 pf = *(const short8*)&QP[w * 16 + l16][c * 32 + quad * 8];
#pragma unroll
        for (int d4 = 0; d4 < 4; d4++) {
          int row = d4 * 16 + l16;
          int ch = ((c * 4 + quad) ^ (2 * d4 + (l16 >> 3))) * 16;
          short8 vf = *(const short8*)((const char*)&Vts[buf][row][0] + ch);
          accB[d4] = __builtin_amdgcn_mfma_f32_16x16x32_bf16(pf, vf, accB[d4], 0, 0, 0);
        }
      }
      __builtin_amdgcn_s_setprio(0);
    }

    // ---- late V transpose into other buffer (UNCONDITIONAL; V loads had full-iter cover)
#pragma unroll
    for (int i = 0; i < 8; i++) {
      int row = vd0 + i;
      int ch = ((vkp >> 2) ^ (t & 7)) * 16 + (vkp & 3) * 4;
      *(unsigned*)((char*)&Vts[nb][row][0] + ch) =
          (unsigned)va.e[i] | ((unsigned)vb.e[i] << 16);
    }

    __syncthreads();  // next tile ready (DMA drained); buf reads done before reuse
  }

  // -------- epilogue: row-sum reduce, O = acc / l for both tiles --------
#pragma unroll
  for (int r = 0; r < 4; r++) {
    float sa = slA[r];
    sa += __shfl_xor(sa, 1); sa += __shfl_xor(sa, 2);
    sa += __shfl_xor(sa, 4); sa += __shfl_xor(sa, 8);
    float ia = 1.0f / sa;
    u16* oa = O + obase + (size_t)(rA + r) * Dm;
#pragma unroll
    for (int d4 = 0; d4 < 4; d4++) oa[d4 * 16 + l16] = f2bf(accA[d4][r] * ia);

    float sb = slB[r];
    sb += __shfl_xor(sb, 1); sb += __shfl_xor(sb, 2);
    sb += __shfl_xor(sb, 4); sb += __shfl_xor(sb, 8);
    float ib = 1.0f / sb;
    u16* ob = O + obase + (size_t)(rB + r) * Dm;
#pragma unroll
    for (int d4 = 0; d4 < 4; d4++) ob[d4 * 16 + l16] = f2bf(accB[d4][r] * ib);
  }
}

extern "C" void kernel_launch(void* const* d_in, const int* in_sizes, int n_in,
                              void* d_out, int out_size, void* d_ws, size_t ws_size,
                              hipStream_t stream) {
  const float* x = (const float*)d_in[0];
  const float* rb = (const float*)d_in[1];
  const float* wq = (const float*)d_in[2];
  const float* bq = (const float*)d_in[3];
  const float* wk = (const float*)d_in[4];
  const float* bk = (const float*)d_in[5];
  const float* wv = (const float*)d_in[6];
  const float* bv = (const float*)d_in[7];
  const float* wo = (const float*)d_in[8];
  const float* bo = (const float*)d_in[9];
  const float* n1w = (const float*)d_in[10];
  const float* n2w = (const float*)d_in[11];
  const float* w1 = (const float*)d_in[12];
  const float* b1 = (const float*)d_in[13];
  const float* w2 = (const float*)d_in[14];
  const float* b2 = (const float*)d_in[15];

  const int M = 8192, D = 1024, F = 4096;

  char* wsp = (char*)d_ws;
  u16* h = (u16*)(wsp);
  u16* ao = (u16*)(wsp);
  u16* f1 = (u16*)(wsp);
  u16* qkv = (u16*)(wsp + 16 * MB);
  u16* x1b = (u16*)(wsp + 64 * MB);
  u16* h2 = (u16*)(wsp + 80 * MB);
  float* bqkv = (float*)(wsp + 80 * MB);
  u16* wqkvb = (u16*)(wsp + 96 * MB);
  u16* wob = (u16*)(wsp + 102 * MB);
  u16* w1b = (u16*)(wsp + 104 * MB);
  u16* w2b = (u16*)(wsp + 96 * MB);

  dim3 blk(256);

  cvt_k<<<1024, blk, 0, stream>>>(wq, wqkvb, (D * D) / 4);
  cvt_k<<<1024, blk, 0, stream>>>(wk, wqkvb + D * D, (D * D) / 4);
  cvt_k<<<1024, blk, 0, stream>>>(wv, wqkvb + 2 * D * D, (D * D) / 4);
  cvt_k<<<1024, blk, 0, stream>>>(wo, wob, (D * D) / 4);
  cvt_k<<<4096, blk, 0, stream>>>(w1, w1b, (F * D) / 4);
  hipMemcpyAsync(bqkv, bq, D * 4, hipMemcpyDeviceToDevice, stream);
  hipMemcpyAsync(bqkv + D, bk, D * 4, hipMemcpyDeviceToDevice, stream);
  hipMemcpyAsync(bqkv + 2 * D, bv, D * 4, hipMemcpyDeviceToDevice, stream);

  rmsnorm_k<<<M, blk, 0, stream>>>(x, n1w, h);
  gemm_mfma<0><<<dim3(3 * D / 128, M / 128), blk, 0, stream>>>(
      h, wqkvb, bqkv, nullptr, qkv, M, 3 * D, D);
  attn_mfma_k<<<dim3(16, 64), blk, 0, stream>>>(qkv, rb, ao);
  gemm_mfma<3><<<dim3(D / 128, M / 128), blk, 0, stream>>>(
      ao, wob, bo, x, x1b, M, D, D);
  cvt_k<<<4096, blk, 0, stream>>>(w2, w2b, (D * F) / 4);
  rmsnorm_bf_k<<<M, blk, 0, stream>>>(x1b, n2w, h2);
  gemm_mfma<1><<<dim3(F / 128, M / 128), blk, 0, stream>>>(
      h2, w1b, b1, nullptr, f1, M, F, D);
  gemm_mfma<4><<<dim3(D / 128, M / 128), blk, 0, stream>>>(
      f1, w2b, b2, x1b, d_out, M, D, F);
}